// Round 9
// baseline (161.280 us; speedup 1.0000x reference)
//
#include <hip/hip_runtime.h>

// DDLG autoencoder, fully fused, batch-tile 4, fp16 packed compute.
//   out[b][o] = sum_f prob[o][f] * op_f(x[b][idx[o][0..7]])
// R1: divide-free Einstein reductions via homomorphisms:
//     ein-product = 2D/(N+D),  D=prod(f), N=prod(2-f)
//     ein-sum     = (N-D)/(N+D), N=prod(1+f), D=prod(1-f)
// R5: 48 KB LDS, 1024-thr blocks, 2 blocks/CU (measured-best residency).
// R8: combined-denominator finale (one rcp pair per h2 over s1*s2; range
//     proof: s1*s2 <= 2.25^8 + 257 ~ 914 < 65504, numerators <= 912).
// R14: chain init/step in explicit VOP3P inline asm -- WIN (-5% fused,
//     -13% VALU-busy): hipcc's pk lowering is leaky; asm recovers it.
// R15 (this round): finale in VOP3P asm too, with op_sel P-BROADCAST:
//     v_pk_* reads P01.lo / P01.hi / P23.lo / P23.hi directly from the
//     packed probs register (op_sel/op_sel_hi per-source half select),
//     deleting all 4 splat sequences per gate. Only the 2 v_rcp_f16 per
//     half stay C++. Same structure/LDS/staging as R8.
//     LDS overlays (fp16 rows of 4 = 8 B, ds_read_b64 gathers):
//       x @ [0,16384) | h0 @ [16384,24576) | h1 @ [0,4096) | h2 @ [16384,24576)

typedef _Float16 h2 __attribute__((ext_vector_type(2)));
typedef _Float16 h4 __attribute__((ext_vector_type(4)));

__device__ __forceinline__ float fastrcp(float x) { return __builtin_amdgcn_rcpf(x); }
__device__ __forceinline__ _Float16 hrcp(_Float16 x) {
#if __has_builtin(__builtin_amdgcn_rcph)
    return __builtin_amdgcn_rcph(x);
#else
    return (_Float16)__builtin_amdgcn_rcpf((float)x);
#endif
}
__device__ __forceinline__ unsigned packh2(float a, float b) {
    h2 v = {(_Float16)a, (_Float16)b};
    return __builtin_bit_cast(unsigned, v);
}
__device__ __forceinline__ h2 ash2(unsigned u) { return __builtin_bit_cast(h2, u); }

// ---------------- forced VOP3P packed-fp16 ops (2 elems / 1 inst) ----------------
__device__ __forceinline__ unsigned pk_min(unsigned a, unsigned b) {
    unsigned d; asm("v_pk_min_f16 %0, %1, %2" : "=v"(d) : "v"(a), "v"(b)); return d;
}
__device__ __forceinline__ unsigned pk_max(unsigned a, unsigned b) {
    unsigned d; asm("v_pk_max_f16 %0, %1, %2" : "=v"(d) : "v"(a), "v"(b)); return d;
}
__device__ __forceinline__ unsigned pk_mul(unsigned a, unsigned b) {
    unsigned d; asm("v_pk_mul_f16 %0, %1, %2" : "=v"(d) : "v"(a), "v"(b)); return d;
}
__device__ __forceinline__ unsigned pk_add(unsigned a, unsigned b) {
    unsigned d; asm("v_pk_add_f16 %0, %1, %2" : "=v"(d) : "v"(a), "v"(b)); return d;
}
__device__ __forceinline__ unsigned pk_sub(unsigned a, unsigned b) {   // a - b
    unsigned d;
    asm("v_pk_add_f16 %0, %1, %2 neg_lo:[0,1] neg_hi:[0,1]" : "=v"(d) : "v"(a), "v"(b));
    return d;
}
__device__ __forceinline__ unsigned pk_fma(unsigned a, unsigned b, unsigned c) { // a*b+c
    unsigned d;
    asm("v_pk_fma_f16 %0, %1, %2, %3" : "=v"(d) : "v"(a), "v"(b), "v"(c));
    return d;
}
__device__ __forceinline__ unsigned pk_fnma(unsigned a, unsigned b, unsigned c) { // c-a*b
    unsigned d;
    asm("v_pk_fma_f16 %0, %1, %2, %3 neg_lo:[1,0,0] neg_hi:[1,0,0]"
        : "=v"(d) : "v"(a), "v"(b), "v"(c));
    return d;
}
// a * broadcast(b.lo)  -- both result halves read b's LOW half
__device__ __forceinline__ unsigned pk_mul_blo(unsigned a, unsigned b) {
    unsigned d;
    asm("v_pk_mul_f16 %0, %1, %2 op_sel:[0,0] op_sel_hi:[1,0]" : "=v"(d) : "v"(a), "v"(b));
    return d;
}
// a * broadcast(b.hi) + c
__device__ __forceinline__ unsigned pk_fma_bhi(unsigned a, unsigned b, unsigned c) {
    unsigned d;
    asm("v_pk_fma_f16 %0, %1, %2, %3 op_sel:[0,1,0] op_sel_hi:[1,1,1]"
        : "=v"(d) : "v"(a), "v"(b), "v"(c));
    return d;
}

#define PK_ONE 0x3C003C00u   // {1.0h, 1.0h}
#define PK_TWO 0x40004000u   // {2.0h, 2.0h}

// ---------------- prep: fp16 prob table only ----------------
// probsH: [0,2048) L0 | [2048,3072) L1 | [3072,5120) L2 | [5120,9216) L3
__global__ __launch_bounds__(256) void prep_k(const float* __restrict__ w0,
                                              const float* __restrict__ w1,
                                              const float* __restrict__ w2,
                                              const float* __restrict__ w3,
                                              const int* __restrict__ is_train,
                                              h4* __restrict__ probsH) {
    const int g = blockIdx.x * 256 + threadIdx.x;   // grid 36 -> 9216 exact
    const float* w; int o;
    if (g < 2048)      { w = w0; o = g; }
    else if (g < 3072) { w = w1; o = g - 2048; }
    else if (g < 5120) { w = w2; o = g - 3072; }
    else               { w = w3; o = g - 5120; }
    float wv[4];
#pragma unroll
    for (int c = 0; c < 4; ++c) wv[c] = w[(o << 2) + c];
    float p[4];
    if (*is_train) {
        float m = fmaxf(fmaxf(wv[0], wv[1]), fmaxf(wv[2], wv[3]));
        float s = 0.0f;
#pragma unroll
        for (int c = 0; c < 4; ++c) { p[c] = __expf(wv[c] - m); s += p[c]; }
        float inv = fastrcp(s);
#pragma unroll
        for (int c = 0; c < 4; ++c) p[c] *= inv;
    } else {
        int a = 0; float best = wv[0];
#pragma unroll
        for (int c = 1; c < 4; ++c) if (wv[c] > best) { best = wv[c]; a = c; }
#pragma unroll
        for (int c = 0; c < 4; ++c) p[c] = (c == a) ? 1.0f : 0.0f;
    }
    probsH[g] = h4{(_Float16)p[0], (_Float16)p[1], (_Float16)p[2], (_Float16)p[3]};
}

// ---------------- chain state: 6 reductions x 2 packed halves, in uint bits ----
struct Chain { unsigned mn0, mn1, mx0, mx1, De0, De1, Ne0, Ne1, Nc0, Nc1, Dc0, Dc1; };

__device__ __forceinline__ void cinit(Chain& C, uint2 v) {
    C.mn0 = v.x; C.mx0 = v.x; C.De0 = v.x;
    C.Ne0 = pk_sub(PK_TWO, v.x); C.Nc0 = pk_add(PK_ONE, v.x); C.Dc0 = pk_sub(PK_ONE, v.x);
    C.mn1 = v.y; C.mx1 = v.y; C.De1 = v.y;
    C.Ne1 = pk_sub(PK_TWO, v.y); C.Nc1 = pk_add(PK_ONE, v.y); C.Dc1 = pk_sub(PK_ONE, v.y);
}
__device__ __forceinline__ void cstep(Chain& C, uint2 v) {
    C.mn0 = pk_min(C.mn0, v.x);            C.mn1 = pk_min(C.mn1, v.y);
    C.mx0 = pk_max(C.mx0, v.x);            C.mx1 = pk_max(C.mx1, v.y);
    C.De0 = pk_mul(C.De0, v.x);            C.De1 = pk_mul(C.De1, v.y);
    const unsigned w0 = pk_sub(PK_TWO, v.x), w1 = pk_sub(PK_TWO, v.y);
    C.Ne0 = pk_mul(C.Ne0, w0);             C.Ne1 = pk_mul(C.Ne1, w1);
    C.Nc0 = pk_fma(C.Nc0, v.x, C.Nc0);     C.Nc1 = pk_fma(C.Nc1, v.y, C.Nc1);   // *= (1+v)
    C.Dc0 = pk_fnma(C.Dc0, v.x, C.Dc0);    C.Dc1 = pk_fnma(C.Dc1, v.y, C.Dc1);  // *= (1-v)
}

// combined-denominator finale, all-pk with op_sel P broadcast.
// P01 = {P0,P1} packed, P23 = {P2,P3} packed (one uint2 load from probsH).
__device__ __forceinline__ unsigned finale_half(unsigned mn, unsigned mx,
                                                unsigned De, unsigned Ne,
                                                unsigned Nc, unsigned Dc,
                                                unsigned P01, unsigned P23) {
    const unsigned s1 = pk_add(Ne, De);          // [1, 257]
    const unsigned s2 = pk_add(Nc, Dc);          // [1, 257]
    const unsigned d1 = pk_sub(Nc, Dc);          // [0, 256]
    const unsigned ss = pk_mul(s1, s2);          // <= ~914: fp16-safe
    const h2 ssh = ash2(ss);
    h2 rh = {hrcp(ssh[0]), hrcp(ssh[1])};        // 2x v_rcp_f16 + pack
    const unsigned r  = __builtin_bit_cast(unsigned, rh);
    const unsigned t1 = pk_mul(pk_add(De, De), s2);   // 2*De*s2 <= 514
    const unsigned t2 = pk_mul(d1, s1);               // <= 912
    const unsigned num  = pk_fma_bhi(t2, P23, pk_mul_blo(t1, P23));  // P2*t1+P3*t2
    const unsigned base = pk_fma_bhi(mx, P01, pk_mul_blo(mn, P01));  // P0*mn+P1*mx
    return pk_fma(num, r, base);
}

__device__ __forceinline__ uint2 finale(const Chain& C, uint2 P) {
    return uint2{finale_half(C.mn0, C.mx0, C.De0, C.Ne0, C.Nc0, C.Dc0, P.x, P.y),
                 finale_half(C.mn1, C.mx1, C.De1, C.Ne1, C.Nc1, C.Dc1, P.x, P.y)};
}

// ---------------- one gate, 4 batch lanes ----------------
__device__ __forceinline__ uint2 gate(const uint2* __restrict__ rows,
                                      const int4* __restrict__ idx,
                                      const uint2* __restrict__ probs, int o) {
    const int4 i0 = idx[o * 2], i1 = idx[o * 2 + 1];
    const uint2 P = probs[o];                    // {P01, P23}
    uint2 A[8];
    A[0] = rows[i0.x]; A[1] = rows[i0.y]; A[2] = rows[i0.z]; A[3] = rows[i0.w];
    A[4] = rows[i1.x]; A[5] = rows[i1.y]; A[6] = rows[i1.z]; A[7] = rows[i1.w];
    Chain C; cinit(C, A[0]);
#pragma unroll
    for (int c = 1; c < 8; ++c) cstep(C, A[c]);
    return finale(C, P);
}

// ---------------- the fused network ----------------
// grid = 1024 (one block per 4-batch tile), block = 1024, 48 KB, 2 blocks/CU
__global__ __launch_bounds__(1024, 8) void ddlg_fused(const float* __restrict__ x,
                                                      const uint2* __restrict__ probsH,
                                                      const int4* __restrict__ idx0,
                                                      const int4* __restrict__ idx1,
                                                      const int4* __restrict__ idx2,
                                                      const int4* __restrict__ idx3,
                                                      float* __restrict__ out) {
    __shared__ __align__(16) _Float16 lds[24576];   // 48 KB
    const int t  = threadIdx.x;
    const int b0 = blockIdx.x << 2;

    const uint2* xl  = (const uint2*)lds;            // rows [0,4096)
    const uint2* h0v = (const uint2*)(lds + 16384);  // rows [0,2048)
    const uint2* h1v = (const uint2*)lds;            // rows [0,1024) (over dead x)
    const uint2* h2v = (const uint2*)(lds + 16384);  // rows [0,2048) (over dead h0)
    uint2* const h0w = (uint2*)(lds + 16384);
    uint2* const h1w = (uint2*)lds;

    // ---- stage x: thread owns rows j = t + 1024c; 4 coalesced loads -> b64 ----
#pragma unroll
    for (int c = 0; c < 4; ++c) {
        const int j = (c << 10) + t;
        const float v0 = x[(size_t)(b0 + 0) * 4096 + j];
        const float v1 = x[(size_t)(b0 + 1) * 4096 + j];
        const float v2 = x[(size_t)(b0 + 2) * 4096 + j];
        const float v3 = x[(size_t)(b0 + 3) * 4096 + j];
        ((uint2*)lds)[j] = uint2{packh2(v0, v1), packh2(v2, v3)};
    }
    __syncthreads();

    // ---- L0: 4096 -> 2048, o = t, t+1024 ----
#pragma unroll
    for (int k = 0; k < 2; ++k) {
        const int o = (k << 10) + t;
        h0w[o] = gate(xl, idx0, probsH, o);
    }
    __syncthreads();

    // ---- L1: 2048 -> 1024, o = t ----
    h1w[t] = gate(h0v, idx1, probsH + 2048, t);
    __syncthreads();

    // ---- L2: 1024 -> 2048, o = t, t+1024 ----
#pragma unroll
    for (int k = 0; k < 2; ++k) {
        const int o = (k << 10) + t;
        h0w[o] = gate(h1v, idx2, probsH + 3072, o);   // h2 over dead h0
    }
    __syncthreads();

    // ---- L3: 2048 -> 4096, o = t + 1024k; coalesced dword stores ----
#pragma unroll
    for (int k = 0; k < 4; ++k) {
        const int o = (k << 10) + t;
        uint2 r = gate(h2v, idx3, probsH + 5120, o);
        h2 lo = ash2(r.x), hi = ash2(r.y);
        out[(size_t)(b0 + 0) * 4096 + o] = (float)lo[0];
        out[(size_t)(b0 + 1) * 4096 + o] = (float)lo[1];
        out[(size_t)(b0 + 2) * 4096 + o] = (float)hi[0];
        out[(size_t)(b0 + 3) * 4096 + o] = (float)hi[1];
    }
}

extern "C" void kernel_launch(void* const* d_in, const int* in_sizes, int n_in,
                              void* d_out, int out_size, void* d_ws, size_t ws_size,
                              hipStream_t stream) {
    const float* x        = (const float*)d_in[0];
    const float* w0       = (const float*)d_in[1];
    const float* w1       = (const float*)d_in[2];
    const float* w2       = (const float*)d_in[3];
    const float* w3       = (const float*)d_in[4];
    const int4*  idx0     = (const int4*)d_in[5];
    const int4*  idx1     = (const int4*)d_in[6];
    const int4*  idx2     = (const int4*)d_in[7];
    const int4*  idx3     = (const int4*)d_in[8];
    const int*   is_train = (const int*)d_in[9];
    float*       out      = (float*)d_out;

    // ws: probsH 9216*8B = 72 KB @0
    h4* probsH = (h4*)d_ws;

    prep_k<<<36, 256, 0, stream>>>(w0, w1, w2, w3, is_train, probsH);
    ddlg_fused<<<1024, 1024, 0, stream>>>(x, (const uint2*)probsH,
                                          idx0, idx1, idx2, idx3, out);
}